// Round 2
// baseline (3047.403 us; speedup 1.0000x reference)
//
#include <hip/hip_runtime.h>

#define NF 16384
#define NB 4096
#define EF 262144
#define EB 65536
#define FBLK 1024   // EF/256
#define BBLK 256    // EB/256

// ---------------------------------------------------------------------------
// K1: per-edge tent-basis cells/weights + per-block cell histogram.
// Tent basis on 8 centers over [-1,1]: at most 2 nonzero per axis -> 4 cells.
// Signed-zero care: reference computes d = sign*(src-tgt)/support; for
// self-edges (src==tgt) this is (-0,-0) for fluid (sign=-1) and IEEE
// atan2(-0,-0) = -pi selects tent iv=0 — must match exactly.
// ---------------------------------------------------------------------------
__global__ void basis_hist_kernel(const float* __restrict__ posT,
                                  const float* __restrict__ posS,
                                  const int* __restrict__ tgt,
                                  const int* __restrict__ src,
                                  const float* __restrict__ supportp,
                                  float sign,
                                  uchar4* __restrict__ cells,
                                  float4* __restrict__ wts,
                                  int* __restrict__ hist) {
  __shared__ int lh[64];
  int t = threadIdx.x;
  if (t < 64) lh[t] = 0;
  __syncthreads();
  int e = blockIdx.x * 256 + t;
  float inv_sup = 1.0f / supportp[0];
  int ti = tgt[e], si = src[e];
  const float2* pT2 = (const float2*)posT;
  const float2* pS2 = (const float2*)posS;
  float2 pt = pT2[ti];
  float2 ps = pS2[si];
  // d = sign * (src - tgt) / support  — sign=-1 fluid, +1 boundary.
  // IEEE: (-1)*(+0) = -0, preserving the reference's -(0) = -0.
  float dx = sign * ((ps.x - pt.x) * inv_sup);
  float dy = sign * ((ps.y - pt.y) * inv_sup);
  dx = fminf(fmaxf(dx, -1.f), 1.f);
  dy = fminf(fmaxf(dy, -1.f), 1.f);
  float r = sqrtf(dx * dx + dy * dy + 1e-12f);
  float theta;
  if (dx == 0.0f && dy == 0.0f) {
    // explicit IEEE atan2 zero semantics: atan2(+-0, -0) = +-pi, atan2(+-0, +0) = +-0
    float mag = __builtin_signbitf(dx) ? 3.14159265358979323846f : 0.0f;
    theta = __builtin_signbitf(dy) ? -mag : mag;
  } else {
    theta = atan2f(dy, dx);
  }
  float u = 2.f * r - 1.f;
  float v = theta * (1.f / 3.14159265358979323846f);
  float tu = (u + 1.f) * 3.5f;   // (u+1)/spacing, spacing = 2/7
  float tv = (v + 1.f) * 3.5f;
  int iu = min(max((int)floorf(tu), 0), 6);
  int iv = min(max((int)floorf(tv), 0), 6);
  float wu0 = fmaxf(0.f, 1.f - fabsf(tu - (float)iu));
  float wu1 = fmaxf(0.f, 1.f - fabsf(tu - (float)(iu + 1)));
  float wv0 = fmaxf(0.f, 1.f - fabsf(tv - (float)iv));
  float wv1 = fmaxf(0.f, 1.f - fabsf(tv - (float)(iv + 1)));
  int c00 = iu * 8 + iv;
  cells[e] = make_uchar4((unsigned char)c00, (unsigned char)(c00 + 1),
                         (unsigned char)(c00 + 8), (unsigned char)(c00 + 9));
  wts[e] = make_float4(wu0 * wv0, wu0 * wv1, wu1 * wv0, wu1 * wv1);
  atomicAdd(&lh[c00], 1);
  atomicAdd(&lh[c00 + 1], 1);
  atomicAdd(&lh[c00 + 8], 1);
  atomicAdd(&lh[c00 + 9], 1);
  __syncthreads();
  if (t < 64) hist[blockIdx.x * 64 + t] = lh[t];
}

// ---------------------------------------------------------------------------
// K2: single-wave scan: per-cell totals, exclusive scan, per-block bases.
// ---------------------------------------------------------------------------
__global__ void scan_kernel(const int* __restrict__ hist, int nblocks,
                            int* __restrict__ blockbase, int* __restrict__ cell_start) {
  int c = threadIdx.x;  // 0..63, one wave
  int tot = 0;
  for (int b = 0; b < nblocks; b++) tot += hist[b * 64 + c];
  int s = tot;
  for (int off = 1; off < 64; off <<= 1) {
    int o = __shfl_up(s, off, 64);
    if (c >= off) s += o;
  }
  int excl = s - tot;
  cell_start[c] = excl;
  if (c == 63) cell_start[64] = excl + tot;
  int run = excl;
  for (int b = 0; b < nblocks; b++) {
    blockbase[b * 64 + c] = run;
    run += hist[b * 64 + c];
  }
}

// ---------------------------------------------------------------------------
// K3: scatter instance ids (e*4+j) into cell-sorted order.
// ---------------------------------------------------------------------------
__global__ void scatter_kernel(const uchar4* __restrict__ cells,
                               const int* __restrict__ blockbase,
                               int* __restrict__ inst_id) {
  __shared__ int cur[64];
  int t = threadIdx.x;
  if (t < 64) cur[t] = blockbase[blockIdx.x * 64 + t];
  __syncthreads();
  int e = blockIdx.x * 256 + t;
  uchar4 c4 = cells[e];
  int p;
  p = atomicAdd(&cur[c4.x], 1); inst_id[p] = e * 4 + 0;
  p = atomicAdd(&cur[c4.y], 1); inst_id[p] = e * 4 + 1;
  p = atomicAdd(&cur[c4.z], 1); inst_id[p] = e * 4 + 2;
  p = atomicAdd(&cur[c4.w], 1); inst_id[p] = e * 4 + 3;
}

// ---------------------------------------------------------------------------
// Conv, cout=64. One wave per instance iteration, lane = output channel.
// W column for this cell cached in VGPRs; x row via broadcast float4 loads.
// ---------------------------------------------------------------------------
template <int CIN>
__global__ void conv_cell64(const int* __restrict__ inst_id,
                            const float* __restrict__ wflat,
                            const int* __restrict__ cell_start,
                            const int* __restrict__ tgt_idx,
                            const int* __restrict__ src_idx,
                            const float* __restrict__ x,
                            const float* __restrict__ W,
                            float* __restrict__ out, int chunks) {
  int cell = blockIdx.x / chunks;
  int chunk = blockIdx.x - cell * chunks;
  int lane = threadIdx.x & 63;
  int wid = threadIdx.x >> 6;
  int s = cell_start[cell], epos = cell_start[cell + 1];
  float Wreg[CIN];
  const float* Wc = W + cell * (CIN * 64) + lane;
#pragma unroll
  for (int ci = 0; ci < CIN; ci++) Wreg[ci] = Wc[ci * 64];
  for (int i = s + chunk * 4 + wid; i < epos; i += chunks * 4) {
    int inst = inst_id[i];
    int e = inst >> 2;
    float w = wflat[inst];
    int tg = tgt_idx[e], sr = src_idx[e];
    const float4* __restrict__ xr = (const float4*)(x + sr * CIN);
    float a0 = 0.f, a1 = 0.f, a2 = 0.f, a3 = 0.f;
#pragma unroll
    for (int q = 0; q < CIN / 4; q++) {
      float4 xv = xr[q];
      a0 = fmaf(xv.x, Wreg[4 * q + 0], a0);
      a1 = fmaf(xv.y, Wreg[4 * q + 1], a1);
      a2 = fmaf(xv.z, Wreg[4 * q + 2], a2);
      a3 = fmaf(xv.w, Wreg[4 * q + 3], a3);
    }
    atomicAdd(out + tg * 64 + lane, ((a0 + a1) + (a2 + a3)) * w);
  }
}

// ---------------------------------------------------------------------------
// Conv, cin=4, cout=32 (W0/W1). Two instances per wave (half-wave each).
// Output row stride fixed 96 (writes into ans0 columns [off, off+32)).
// ---------------------------------------------------------------------------
__global__ void conv_cell32(const int* __restrict__ inst_id,
                            const float* __restrict__ wflat,
                            const int* __restrict__ cell_start,
                            const int* __restrict__ tgt_idx,
                            const int* __restrict__ src_idx,
                            const float* __restrict__ x,
                            const float* __restrict__ W,  // [64][4][32]
                            float* __restrict__ out, int out_off, int chunks) {
  int cell = blockIdx.x / chunks;
  int chunk = blockIdx.x - cell * chunks;
  int lane = threadIdx.x & 63;
  int wid = threadIdx.x >> 6;
  int half = lane >> 5;
  int co = lane & 31;
  int s = cell_start[cell], epos = cell_start[cell + 1];
  const float* Wc = W + cell * 128 + co;
  float W0r = Wc[0], W1r = Wc[32], W2r = Wc[64], W3r = Wc[96];
  for (int base = s + (chunk * 4 + wid) * 2; base < epos; base += chunks * 8) {
    int i = base + half;
    if (i < epos) {
      int inst = inst_id[i];
      int e = inst >> 2;
      float w = wflat[inst];
      int tg = tgt_idx[e], sr = src_idx[e];
      float4 xv = *(const float4*)(x + sr * 4);
      float acc = xv.x * W0r + xv.y * W1r + xv.z * W2r + xv.w * W3r;
      atomicAdd(out + tg * 96 + out_off + co, acc * w);
    }
  }
}

// ---------------------------------------------------------------------------
// Conv, cin=64, cout=2 (W4). One wave per instance, lane = ci, wave-reduce.
// ---------------------------------------------------------------------------
__global__ void conv_cell2(const int* __restrict__ inst_id,
                           const float* __restrict__ wflat,
                           const int* __restrict__ cell_start,
                           const int* __restrict__ tgt_idx,
                           const int* __restrict__ src_idx,
                           const float* __restrict__ x,
                           const float* __restrict__ W,  // [64][64][2]
                           float* __restrict__ out, int chunks) {
  int cell = blockIdx.x / chunks;
  int chunk = blockIdx.x - cell * chunks;
  int lane = threadIdx.x & 63;
  int wid = threadIdx.x >> 6;
  int s = cell_start[cell], epos = cell_start[cell + 1];
  float w0 = W[cell * 128 + lane * 2 + 0];
  float w1 = W[cell * 128 + lane * 2 + 1];
  for (int i = s + chunk * 4 + wid; i < epos; i += chunks * 4) {
    int inst = inst_id[i];
    int e = inst >> 2;
    float w = wflat[inst];
    int tg = tgt_idx[e], sr = src_idx[e];
    float xv = x[sr * 64 + lane];
    float m0 = xv * w0, m1 = xv * w1;
#pragma unroll
    for (int off = 32; off > 0; off >>= 1) {
      m0 += __shfl_xor(m0, off, 64);
      m1 += __shfl_xor(m1, off, 64);
    }
    if (lane == 0) {
      atomicAdd(out + tg * 2 + 0, m0 * w);
      atomicAdd(out + tg * 2 + 1, m1 * w);
    }
  }
}

// ---------------------------------------------------------------------------
// Stage-1 finalize: lin = relu(ff@fc0) into cols 0..31; relu conv cols 32..95.
// ---------------------------------------------------------------------------
__global__ void finalize1(const float* __restrict__ ff, const float* __restrict__ fc0,
                          float* __restrict__ ans0) {
  int gt = blockIdx.x * 256 + threadIdx.x;
  int row = gt >> 6;
  int lane = gt & 63;
  float v = ans0[row * 96 + 32 + lane];
  ans0[row * 96 + 32 + lane] = fmaxf(v, 0.f);
  if (lane < 32) {
    float4 f = *(const float4*)(ff + row * 4);
    float a = f.x * fc0[lane] + f.y * fc0[32 + lane] + f.z * fc0[64 + lane] +
              f.w * fc0[96 + lane];
    ans0[row * 96 + lane] = fmaxf(a, 0.f);
  }
}

// ---------------------------------------------------------------------------
// acc = conv_acc (+ resid) + xin@fc ; optional relu ; in-place on acc buffer.
// One wave handles rows_per_wave rows, fc cached in VGPRs (lane = col).
// ---------------------------------------------------------------------------
template <int CIN, int RELU, int RESID>
__global__ void gemm_finalize(const float* __restrict__ xin, const float* __restrict__ fc,
                              float* __restrict__ accio, const float* __restrict__ resid,
                              int rows_per_wave) {
  int lane = threadIdx.x & 63;
  int gw = (blockIdx.x * 256 + threadIdx.x) >> 6;
  float Wreg[CIN];
#pragma unroll
  for (int ci = 0; ci < CIN; ci++) Wreg[ci] = fc[ci * 64 + lane];
  int r0 = gw * rows_per_wave;
  for (int r = r0; r < r0 + rows_per_wave; r++) {
    const float4* xr = (const float4*)(xin + r * CIN);
    float a0 = accio[r * 64 + lane];
    if (RESID) a0 += resid[r * 64 + lane];
    float a1 = 0.f, a2 = 0.f, a3 = 0.f;
#pragma unroll
    for (int q = 0; q < CIN / 4; q++) {
      float4 xv = xr[q];
      a0 = fmaf(xv.x, Wreg[4 * q + 0], a0);
      a1 = fmaf(xv.y, Wreg[4 * q + 1], a1);
      a2 = fmaf(xv.z, Wreg[4 * q + 2], a2);
      a3 = fmaf(xv.w, Wreg[4 * q + 3], a3);
    }
    float a = (a0 + a1) + (a2 + a3);
    accio[r * 64 + lane] = RELU ? fmaxf(a, 0.f) : a;
  }
}

// ---------------------------------------------------------------------------
// Final: out = conv4_acc + ans2@fc3  (nf x 2)
// ---------------------------------------------------------------------------
__global__ void finalize4(const float* __restrict__ ans2, const float* __restrict__ fc3,
                          const float* __restrict__ conv_acc, float* __restrict__ outp) {
  int row = blockIdx.x * 256 + threadIdx.x;
  float a0 = conv_acc[row * 2 + 0];
  float a1 = conv_acc[row * 2 + 1];
  const float4* xr = (const float4*)(ans2 + row * 64);
#pragma unroll
  for (int q = 0; q < 16; q++) {
    float4 xv = xr[q];
    a0 += xv.x * fc3[(4 * q + 0) * 2] + xv.y * fc3[(4 * q + 1) * 2] +
          xv.z * fc3[(4 * q + 2) * 2] + xv.w * fc3[(4 * q + 3) * 2];
    a1 += xv.x * fc3[(4 * q + 0) * 2 + 1] + xv.y * fc3[(4 * q + 1) * 2 + 1] +
          xv.z * fc3[(4 * q + 2) * 2 + 1] + xv.w * fc3[(4 * q + 3) * 2 + 1];
  }
  outp[row * 2 + 0] = a0;
  outp[row * 2 + 1] = a1;
}

// ---------------------------------------------------------------------------
extern "C" void kernel_launch(void* const* d_in, const int* in_sizes, int n_in,
                              void* d_out, int out_size, void* d_ws, size_t ws_size,
                              hipStream_t stream) {
  const float* fp  = (const float*)d_in[0];
  const float* bp  = (const float*)d_in[1];
  const float* ff  = (const float*)d_in[2];
  const float* bfe = (const float*)d_in[3];
  const float* sup = (const float*)d_in[4];
  const int* fi  = (const int*)d_in[5];
  const int* fj  = (const int*)d_in[6];
  const int* bfi = (const int*)d_in[7];
  const int* bb  = (const int*)d_in[8];
  const float* W0 = (const float*)d_in[9];
  const float* W1 = (const float*)d_in[10];
  const float* W2 = (const float*)d_in[11];
  const float* W3 = (const float*)d_in[12];
  const float* W4 = (const float*)d_in[13];
  const float* fc0 = (const float*)d_in[14];
  const float* fc1 = (const float*)d_in[15];
  const float* fc2 = (const float*)d_in[16];
  const float* fc3 = (const float*)d_in[17];
  float* out = (float*)d_out;

  char* w = (char*)d_ws;
  size_t off = 0;
  auto alloc = [&](size_t bytes) {
    char* p = w + off;
    off += (bytes + 255) & ~size_t(255);
    return p;
  };
  float* ans0   = (float*)alloc((size_t)NF * 96 * 4);
  float* ans1   = (float*)alloc((size_t)NF * 64 * 4);
  float* ans2   = (float*)alloc((size_t)NF * 64 * 4);
  float* outpre = (float*)alloc((size_t)NF * 2 * 4);
  size_t zero_bytes = off;
  uchar4* fcells = (uchar4*)alloc((size_t)EF * 4);
  float4* fwts   = (float4*)alloc((size_t)EF * 16);
  uchar4* bcells = (uchar4*)alloc((size_t)EB * 4);
  float4* bwts   = (float4*)alloc((size_t)EB * 16);
  int* fhist = (int*)alloc((size_t)FBLK * 64 * 4);
  int* fbase = (int*)alloc((size_t)FBLK * 64 * 4);
  int* bhist = (int*)alloc((size_t)BBLK * 64 * 4);
  int* bbase = (int*)alloc((size_t)BBLK * 64 * 4);
  int* fcs = (int*)alloc(65 * 4);
  int* bcs = (int*)alloc(65 * 4);
  int* finst = (int*)alloc((size_t)EF * 4 * 4);
  int* binst = (int*)alloc((size_t)EB * 4 * 4);

  hipMemsetAsync(d_ws, 0, zero_bytes, stream);

  // sign = -1 for fluid (d = -(src-tgt)/sup), +1 for boundary (d = (src-tgt)/sup)
  basis_hist_kernel<<<FBLK, 256, 0, stream>>>(fp, fp, fi, fj, sup, -1.f, fcells, fwts, fhist);
  basis_hist_kernel<<<BBLK, 256, 0, stream>>>(fp, bp, bfi, bb, sup, 1.f, bcells, bwts, bhist);
  scan_kernel<<<1, 64, 0, stream>>>(fhist, FBLK, fbase, fcs);
  scan_kernel<<<1, 64, 0, stream>>>(bhist, BBLK, bbase, bcs);
  scatter_kernel<<<FBLK, 256, 0, stream>>>(fcells, fbase, finst);
  scatter_kernel<<<BBLK, 256, 0, stream>>>(bcells, bbase, binst);

  const float* fwf = (const float*)fwts;
  const float* bwf = (const float*)bwts;

  // Stage 1: conv W0 (fluid feats -> cols 32..63), conv W1 (bdy -> cols 64..95)
  conv_cell32<<<64 * 32, 256, 0, stream>>>(finst, fwf, fcs, fi, fj, ff, W0, ans0, 32, 32);
  conv_cell32<<<64 * 8, 256, 0, stream>>>(binst, bwf, bcs, bfi, bb, bfe, W1, ans0, 64, 8);
  finalize1<<<NF / 4, 256, 0, stream>>>(ff, fc0, ans0);

  // Stage 2: ans1 = relu(conv(ans0,W2) + ans0@fc1)
  conv_cell64<96><<<64 * 32, 256, 0, stream>>>(finst, fwf, fcs, fi, fj, ans0, W2, ans1, 32);
  gemm_finalize<96, 1, 0><<<NF / 16 / 4, 256, 0, stream>>>(ans0, fc1, ans1, nullptr, 16);

  // Stage 3: ans2 = relu(conv(ans1,W3) + ans1@fc2 + ans1)
  conv_cell64<64><<<64 * 32, 256, 0, stream>>>(finst, fwf, fcs, fi, fj, ans1, W3, ans2, 32);
  gemm_finalize<64, 1, 1><<<NF / 16 / 4, 256, 0, stream>>>(ans1, fc2, ans2, ans1, 16);

  // Stage 4: out = conv(ans2,W4) + ans2@fc3
  conv_cell2<<<64 * 32, 256, 0, stream>>>(finst, fwf, fcs, fi, fj, ans2, W4, outpre, 32);
  finalize4<<<NF / 256, 256, 0, stream>>>(ans2, fc3, outpre, out);
}

// Round 3
// 2910.380 us; speedup vs baseline: 1.0471x; 1.0471x over previous
//
#include <hip/hip_runtime.h>

#define NF 16384
#define NB 4096
#define EF 262144
#define EB 65536
#define FBLK 1024   // EF/256
#define BBLK 256    // EB/256

// ---------------------------------------------------------------------------
// K1: per-edge tent-basis cells/weights + per-block cell histogram.
// ---------------------------------------------------------------------------
__global__ void __launch_bounds__(256) basis_hist_kernel(
    const float* __restrict__ posT, const float* __restrict__ posS,
    const int* __restrict__ tgt, const int* __restrict__ src,
    const float* __restrict__ supportp, float sign,
    uchar4* __restrict__ cells, float4* __restrict__ wts, int* __restrict__ hist) {
  __shared__ int lh[64];
  int t = threadIdx.x;
  if (t < 64) lh[t] = 0;
  __syncthreads();
  int e = blockIdx.x * 256 + t;
  float inv_sup = 1.0f / supportp[0];
  int ti = tgt[e], si = src[e];
  const float2* pT2 = (const float2*)posT;
  const float2* pS2 = (const float2*)posS;
  float2 pt = pT2[ti];
  float2 ps = pS2[si];
  // d = sign * (src - tgt) / support; sign=-1 fluid, +1 boundary.
  // IEEE: (-1)*(+0) = -0 preserves reference signed zeros for self-edges.
  float dx = sign * ((ps.x - pt.x) * inv_sup);
  float dy = sign * ((ps.y - pt.y) * inv_sup);
  dx = fminf(fmaxf(dx, -1.f), 1.f);
  dy = fminf(fmaxf(dy, -1.f), 1.f);
  float r = sqrtf(dx * dx + dy * dy + 1e-12f);
  float theta;
  if (dx == 0.0f && dy == 0.0f) {
    float mag = __builtin_signbitf(dx) ? 3.14159265358979323846f : 0.0f;
    theta = __builtin_signbitf(dy) ? -mag : mag;
  } else {
    theta = atan2f(dy, dx);
  }
  float u = 2.f * r - 1.f;
  float v = theta * (1.f / 3.14159265358979323846f);
  float tu = (u + 1.f) * 3.5f;
  float tv = (v + 1.f) * 3.5f;
  int iu = min(max((int)floorf(tu), 0), 6);
  int iv = min(max((int)floorf(tv), 0), 6);
  float wu0 = fmaxf(0.f, 1.f - fabsf(tu - (float)iu));
  float wu1 = fmaxf(0.f, 1.f - fabsf(tu - (float)(iu + 1)));
  float wv0 = fmaxf(0.f, 1.f - fabsf(tv - (float)iv));
  float wv1 = fmaxf(0.f, 1.f - fabsf(tv - (float)(iv + 1)));
  int c00 = iu * 8 + iv;
  cells[e] = make_uchar4((unsigned char)c00, (unsigned char)(c00 + 1),
                         (unsigned char)(c00 + 8), (unsigned char)(c00 + 9));
  wts[e] = make_float4(wu0 * wv0, wu0 * wv1, wu1 * wv0, wu1 * wv1);
  atomicAdd(&lh[c00], 1);
  atomicAdd(&lh[c00 + 1], 1);
  atomicAdd(&lh[c00 + 8], 1);
  atomicAdd(&lh[c00 + 9], 1);
  __syncthreads();
  if (t < 64) hist[blockIdx.x * 64 + t] = lh[t];
}

// ---------------------------------------------------------------------------
// K2: single-wave scan over 64 cells.
// ---------------------------------------------------------------------------
__global__ void scan_kernel(const int* __restrict__ hist, int nblocks,
                            int* __restrict__ blockbase, int* __restrict__ cell_start) {
  int c = threadIdx.x;
  int tot = 0;
  for (int b = 0; b < nblocks; b++) tot += hist[b * 64 + c];
  int s = tot;
  for (int off = 1; off < 64; off <<= 1) {
    int o = __shfl_up(s, off, 64);
    if (c >= off) s += o;
  }
  int excl = s - tot;
  cell_start[c] = excl;
  if (c == 63) cell_start[64] = excl + tot;
  int run = excl;
  for (int b = 0; b < nblocks; b++) {
    blockbase[b * 64 + c] = run;
    run += hist[b * 64 + c];
  }
}

// ---------------------------------------------------------------------------
// K3: scatter into cell-sorted order. Writes sorted weight + sorted src
// (streaming reads for phase A) and inst_pos (inverse perm for phase B).
// ---------------------------------------------------------------------------
__global__ void __launch_bounds__(256) scatter_kernel(
    const uchar4* __restrict__ cells, const float4* __restrict__ wts,
    const int* __restrict__ src_idx, const int* __restrict__ blockbase,
    int* __restrict__ inst_pos, float* __restrict__ wsorted, int* __restrict__ srcsorted) {
  __shared__ int cur[64];
  int t = threadIdx.x;
  if (t < 64) cur[t] = blockbase[blockIdx.x * 64 + t];
  __syncthreads();
  int e = blockIdx.x * 256 + t;
  uchar4 c4 = cells[e];
  float4 w4 = wts[e];
  int sr = src_idx[e];
  int p;
  p = atomicAdd(&cur[c4.x], 1); inst_pos[e * 4 + 0] = p; wsorted[p] = w4.x; srcsorted[p] = sr;
  p = atomicAdd(&cur[c4.y], 1); inst_pos[e * 4 + 1] = p; wsorted[p] = w4.y; srcsorted[p] = sr;
  p = atomicAdd(&cur[c4.z], 1); inst_pos[e * 4 + 2] = p; wsorted[p] = w4.z; srcsorted[p] = sr;
  p = atomicAdd(&cur[c4.w], 1); inst_pos[e * 4 + 3] = p; wsorted[p] = w4.w; srcsorted[p] = sr;
}

// ---------------------------------------------------------------------------
// Target CSR build: histogram, scan (16384 bins), scatter edges by target.
// ---------------------------------------------------------------------------
__global__ void __launch_bounds__(256) tgt_hist(const int* __restrict__ tgt, int n,
                                                int* __restrict__ hist) {
  int e = blockIdx.x * 256 + threadIdx.x;
  if (e < n) atomicAdd(hist + tgt[e], 1);
}

__global__ void __launch_bounds__(1024) csr_scan(const int* __restrict__ hist,
                                                 int* __restrict__ start,
                                                 int* __restrict__ cursor) {
  __shared__ int wtot[16];
  int t = threadIdx.x;
  int lane = t & 63, wv = t >> 6;
  int base = t * 16;
  int vals[16];
  int s = 0;
#pragma unroll
  for (int k = 0; k < 16; k++) { vals[k] = hist[base + k]; s += vals[k]; }
  int ss = s;
  for (int off = 1; off < 64; off <<= 1) {
    int o = __shfl_up(ss, off, 64);
    if (lane >= off) ss += o;
  }
  if (lane == 63) wtot[wv] = ss;
  __syncthreads();
  if (t < 16) {
    int v = wtot[t];
    int vv = v;
    for (int off = 1; off < 16; off <<= 1) {
      int o = __shfl_up(vv, off, 64);
      if (t >= off) vv += o;
    }
    wtot[t] = vv - v;
  }
  __syncthreads();
  int run = ss - s + wtot[wv];
#pragma unroll
  for (int k = 0; k < 16; k++) { start[base + k] = run; cursor[base + k] = run; run += vals[k]; }
  if (t == 1023) start[16384] = run;
}

__global__ void __launch_bounds__(256) tgt_scatter(const int* __restrict__ tgt, int n,
                                                   int* __restrict__ cursor,
                                                   int* __restrict__ edges) {
  int e = blockIdx.x * 256 + threadIdx.x;
  if (e < n) { int p = atomicAdd(cursor + tgt[e], 1); edges[p] = e; }
}

// ---------------------------------------------------------------------------
// Phase A, cout=64: wave owns a contiguous sorted-position range; W column for
// the current cell cached in VGPRs; per instance: streaming src/w reads, x-row
// gather, CIN FMAs, one coalesced 256B message store. NO atomics.
// ---------------------------------------------------------------------------
template <int CIN>
__global__ void __launch_bounds__(256) msg_conv64(
    const int* __restrict__ srcsorted, const float* __restrict__ wsorted,
    const int* __restrict__ cell_start, const float* __restrict__ x,
    const float* __restrict__ W, float* __restrict__ msg, int p0, int p1) {
  __shared__ int cs[65];
  if (threadIdx.x < 65) cs[threadIdx.x] = cell_start[threadIdx.x];
  __syncthreads();
  int lane = threadIdx.x & 63;
  int gw = blockIdx.x * 4 + (threadIdx.x >> 6);
  int nw = gridDim.x * 4;
  int total = p1 - p0;
  int per = (total + nw - 1) / nw;
  int i0 = p0 + gw * per;
  int i1 = min(i0 + per, p1);
  if (i0 >= i1) return;
  int cell = 0;
#pragma unroll
  for (int b = 32; b >= 1; b >>= 1)
    if (cell + b <= 63 && cs[cell + b] <= i0) cell += b;
  float Wreg[CIN];
  {
    const float* Wc = W + cell * (CIN * 64) + lane;
#pragma unroll
    for (int ci = 0; ci < CIN; ci++) Wreg[ci] = Wc[ci * 64];
  }
  for (int i = i0; i < i1; i++) {
    if (i >= cs[cell + 1]) {
      do { cell++; } while (i >= cs[cell + 1]);
      const float* Wc = W + cell * (CIN * 64) + lane;
#pragma unroll
      for (int ci = 0; ci < CIN; ci++) Wreg[ci] = Wc[ci * 64];
    }
    int sr = srcsorted[i];
    float w = wsorted[i];
    const float4* __restrict__ xr = (const float4*)(x + (size_t)sr * CIN);
    float a0 = 0.f, a1 = 0.f, a2 = 0.f, a3 = 0.f;
#pragma unroll
    for (int q = 0; q < CIN / 4; q++) {
      float4 xv = xr[q];
      a0 = fmaf(xv.x, Wreg[4 * q + 0], a0);
      a1 = fmaf(xv.y, Wreg[4 * q + 1], a1);
      a2 = fmaf(xv.z, Wreg[4 * q + 2], a2);
      a3 = fmaf(xv.w, Wreg[4 * q + 3], a3);
    }
    msg[(size_t)(i - p0) * 64 + lane] = ((a0 + a1) + (a2 + a3)) * w;
  }
}

// ---------------------------------------------------------------------------
// Phase A, cin=4 cout=32 (W0/W1): two instances per wave (halves), per-lane
// cell tracking, per-instance W loads (L1-hot 8KB table), 256B stores.
// ---------------------------------------------------------------------------
__global__ void __launch_bounds__(256) msg_conv32(
    const int* __restrict__ srcsorted, const float* __restrict__ wsorted,
    const int* __restrict__ cell_start, const float* __restrict__ x,
    const float* __restrict__ W /*[64][4][32]*/, float* __restrict__ msg, int p0, int p1) {
  __shared__ int cs[65];
  if (threadIdx.x < 65) cs[threadIdx.x] = cell_start[threadIdx.x];
  __syncthreads();
  int lane = threadIdx.x & 63;
  int co = lane & 31;
  int half = lane >> 5;
  int gw = blockIdx.x * 4 + (threadIdx.x >> 6);
  int nw = gridDim.x * 4;
  int pairs = (p1 - p0) >> 1;  // ranges are even-sized
  int per = (pairs + nw - 1) / nw;
  int k0 = p0 + gw * per * 2;
  int k1 = min(k0 + per * 2, p1);
  if (k0 >= k1) return;
  int cell = 0;
  for (int k = k0; k < k1; k += 2) {
    int i = k + half;
    while (cs[cell + 1] <= i) cell++;
    int sr = srcsorted[i];
    float w = wsorted[i];
    const float* Wc = W + cell * 128 + co;
    float4 xv = *(const float4*)(x + (size_t)sr * 4);
    float acc = xv.x * Wc[0] + xv.y * Wc[32] + xv.z * Wc[64] + xv.w * Wc[96];
    msg[(size_t)(k - p0) * 32 + lane] = acc * w;
  }
}

// ---------------------------------------------------------------------------
// Phase A, cin=64 cout=2 (W4): wave per instance, lane=ci, shuffle-reduce,
// 8B message store.
// ---------------------------------------------------------------------------
__global__ void __launch_bounds__(256) msg_conv2(
    const int* __restrict__ srcsorted, const float* __restrict__ wsorted,
    const int* __restrict__ cell_start, const float* __restrict__ x,
    const float* __restrict__ W /*[64][64][2]*/, float2* __restrict__ msg, int p0, int p1) {
  __shared__ int cs[65];
  if (threadIdx.x < 65) cs[threadIdx.x] = cell_start[threadIdx.x];
  __syncthreads();
  int lane = threadIdx.x & 63;
  int gw = blockIdx.x * 4 + (threadIdx.x >> 6);
  int nw = gridDim.x * 4;
  int total = p1 - p0;
  int per = (total + nw - 1) / nw;
  int i0 = p0 + gw * per;
  int i1 = min(i0 + per, p1);
  if (i0 >= i1) return;
  int cell = 0;
#pragma unroll
  for (int b = 32; b >= 1; b >>= 1)
    if (cell + b <= 63 && cs[cell + b] <= i0) cell += b;
  float w0 = W[cell * 128 + lane * 2 + 0];
  float w1 = W[cell * 128 + lane * 2 + 1];
  for (int i = i0; i < i1; i++) {
    if (i >= cs[cell + 1]) {
      do { cell++; } while (i >= cs[cell + 1]);
      w0 = W[cell * 128 + lane * 2 + 0];
      w1 = W[cell * 128 + lane * 2 + 1];
    }
    int sr = srcsorted[i];
    float w = wsorted[i];
    float xv = x[(size_t)sr * 64 + lane];
    float m0 = xv * w0, m1 = xv * w1;
#pragma unroll
    for (int off = 32; off > 0; off >>= 1) {
      m0 += __shfl_xor(m0, off, 64);
      m1 += __shfl_xor(m1, off, 64);
    }
    if (lane == 0) msg[i - p0] = make_float2(m0 * w, m1 * w);
  }
}

// ---------------------------------------------------------------------------
// Phase B stage 1: per-target gather of fluid msgs (cols 32..63, chunked) +
// bdy msgs (cols 64..95, pass 0) + lin = relu(ff@fc0) (cols 0..31, pass 0).
// ---------------------------------------------------------------------------
__global__ void __launch_bounds__(256) b1_stage1(
    const float* __restrict__ ff, const float* __restrict__ fc0,
    const int* __restrict__ ftstart, const int* __restrict__ ftedges,
    const int* __restrict__ finstpos, const float* __restrict__ msgF,
    const int* __restrict__ btstart, const int* __restrict__ btedges,
    const int* __restrict__ binstpos, const float* __restrict__ msgB,
    float* __restrict__ ans0, int p0, int p1, int init, int fin) {
  int lane = threadIdx.x & 63;
  int t = blockIdx.x * 4 + (threadIdx.x >> 6);
  int co = lane & 31;
  float f = 0.f;
  int s = ftstart[t], e1 = ftstart[t + 1];
  for (int idx = s; idx < e1; idx++) {
    int e = ftedges[idx];
    int4 p4 = *(const int4*)(finstpos + 4 * e);
    int pa = (lane < 32) ? p4.x : p4.y;
    int pb = (lane < 32) ? p4.z : p4.w;
    if (pa >= p0 && pa < p1) f += msgF[(size_t)(pa - p0) * 32 + co];
    if (pb >= p0 && pb < p1) f += msgF[(size_t)(pb - p0) * 32 + co];
  }
  f += __shfl_xor(f, 32, 64);
  if (!init) f += ans0[t * 96 + 32 + co];
  if (fin) f = fmaxf(f, 0.f);
  if (lane < 32) ans0[t * 96 + 32 + lane] = f;
  if (init) {
    float b = 0.f;
    int bs = btstart[t], be = btstart[t + 1];
    for (int idx = bs; idx < be; idx++) {
      int e = btedges[idx];
      int4 p4 = *(const int4*)(binstpos + 4 * e);
      int pa = (lane < 32) ? p4.x : p4.y;
      int pb = (lane < 32) ? p4.z : p4.w;
      b += msgB[(size_t)pa * 32 + co];
      b += msgB[(size_t)pb * 32 + co];
    }
    b += __shfl_xor(b, 32, 64);
    if (lane >= 32) ans0[t * 96 + 64 + co] = fmaxf(b, 0.f);
    if (lane < 32) {
      float4 fv = *(const float4*)(ff + t * 4);
      float a = fv.x * fc0[lane] + fv.y * fc0[32 + lane] + fv.z * fc0[64 + lane] +
                fv.w * fc0[96 + lane];
      ans0[t * 96 + lane] = fmaxf(a, 0.f);
    }
  }
}

// ---------------------------------------------------------------------------
// Phase B stages 2/3: dest = relu(conv_sum + xin@fc (+resid)); fused epilogue.
// Wave per target; 256B coalesced msg-row gathers.
// ---------------------------------------------------------------------------
template <int CIN, int RESID>
__global__ void __launch_bounds__(256) b23(
    const float* __restrict__ xin, const float* __restrict__ fc,
    const int* __restrict__ ftstart, const int* __restrict__ ftedges,
    const int* __restrict__ finstpos, const float* __restrict__ msg,
    const float* __restrict__ resid, float* __restrict__ dest,
    int p0, int p1, int init, int fin) {
  int lane = threadIdx.x & 63;
  int t = blockIdx.x * 4 + (threadIdx.x >> 6);
  float acc;
  if (init) {
    acc = RESID ? resid[(size_t)t * 64 + lane] : 0.f;
    const float4* __restrict__ xr = (const float4*)(xin + (size_t)t * CIN);
#pragma unroll
    for (int q = 0; q < CIN / 4; q++) {
      float4 xv = xr[q];
      acc = fmaf(xv.x, fc[(4 * q + 0) * 64 + lane], acc);
      acc = fmaf(xv.y, fc[(4 * q + 1) * 64 + lane], acc);
      acc = fmaf(xv.z, fc[(4 * q + 2) * 64 + lane], acc);
      acc = fmaf(xv.w, fc[(4 * q + 3) * 64 + lane], acc);
    }
  } else {
    acc = dest[(size_t)t * 64 + lane];
  }
  int s = ftstart[t], e1 = ftstart[t + 1];
  for (int idx = s; idx < e1; idx++) {
    int e = ftedges[idx];
    int4 p4 = *(const int4*)(finstpos + 4 * e);
    if (p4.x >= p0 && p4.x < p1) acc += msg[(size_t)(p4.x - p0) * 64 + lane];
    if (p4.y >= p0 && p4.y < p1) acc += msg[(size_t)(p4.y - p0) * 64 + lane];
    if (p4.z >= p0 && p4.z < p1) acc += msg[(size_t)(p4.z - p0) * 64 + lane];
    if (p4.w >= p0 && p4.w < p1) acc += msg[(size_t)(p4.w - p0) * 64 + lane];
  }
  dest[(size_t)t * 64 + lane] = fin ? fmaxf(acc, 0.f) : acc;
}

// ---------------------------------------------------------------------------
// Phase B stage 4: out[t] = sum msg2 + ans2@fc3. Wave per target, lane=inst.
// ---------------------------------------------------------------------------
__global__ void __launch_bounds__(256) b4_stage4(
    const float* __restrict__ ans2, const float* __restrict__ fc3,
    const int* __restrict__ ftstart, const int* __restrict__ ftedges,
    const int* __restrict__ finstpos, const float2* __restrict__ msg2,
    float* __restrict__ partial, float* __restrict__ outp,
    int p0, int p1, int init, int fin) {
  int lane = threadIdx.x & 63;
  int t = blockIdx.x * 4 + (threadIdx.x >> 6);
  int s = ftstart[t], e1 = ftstart[t + 1];
  int cnt = (e1 - s) * 4;
  float m0 = 0.f, m1 = 0.f;
  for (int base = 0; base < cnt; base += 64) {
    int idx = base + lane;
    if (idx < cnt) {
      int e = ftedges[s + (idx >> 2)];
      int p = finstpos[e * 4 + (idx & 3)];
      if (p >= p0 && p < p1) {
        float2 mm = msg2[p - p0];
        m0 += mm.x;
        m1 += mm.y;
      }
    }
  }
  if (init) {
    float a = ans2[(size_t)t * 64 + lane];
    m0 += a * fc3[lane * 2 + 0];
    m1 += a * fc3[lane * 2 + 1];
  }
#pragma unroll
  for (int off = 32; off > 0; off >>= 1) {
    m0 += __shfl_xor(m0, off, 64);
    m1 += __shfl_xor(m1, off, 64);
  }
  if (lane == 0) {
    if (!init) { m0 += partial[t * 2]; m1 += partial[t * 2 + 1]; }
    if (fin) { outp[t * 2] = m0; outp[t * 2 + 1] = m1; }
    else { partial[t * 2] = m0; partial[t * 2 + 1] = m1; }
  }
}

// ---------------------------------------------------------------------------
extern "C" void kernel_launch(void* const* d_in, const int* in_sizes, int n_in,
                              void* d_out, int out_size, void* d_ws, size_t ws_size,
                              hipStream_t stream) {
  const float* fp  = (const float*)d_in[0];
  const float* bp  = (const float*)d_in[1];
  const float* ff  = (const float*)d_in[2];
  const float* bfe = (const float*)d_in[3];
  const float* sup = (const float*)d_in[4];
  const int* fi  = (const int*)d_in[5];
  const int* fj  = (const int*)d_in[6];
  const int* bfi = (const int*)d_in[7];
  const int* bb  = (const int*)d_in[8];
  const float* W0 = (const float*)d_in[9];
  const float* W1 = (const float*)d_in[10];
  const float* W2 = (const float*)d_in[11];
  const float* W3 = (const float*)d_in[12];
  const float* W4 = (const float*)d_in[13];
  const float* fc0 = (const float*)d_in[14];
  const float* fc1 = (const float*)d_in[15];
  const float* fc2 = (const float*)d_in[16];
  const float* fc3 = (const float*)d_in[17];
  float* out = (float*)d_out;

  const int TOTF = EF * 4;   // 1,048,576 fluid instances
  const int TOTB = EB * 4;   // 262,144 boundary instances

  char* w = (char*)d_ws;
  size_t off = 0;
  auto alloc = [&](size_t bytes) {
    char* p = w + off;
    off += (bytes + 255) & ~size_t(255);
    return p;
  };
  float* ans0   = (float*)alloc((size_t)NF * 96 * 4);
  float* ans1   = (float*)alloc((size_t)NF * 64 * 4);
  float* ans2   = (float*)alloc((size_t)NF * 64 * 4);
  float* outpre = (float*)alloc((size_t)NF * 2 * 4);
  uchar4* fcells = (uchar4*)alloc((size_t)EF * 4);
  float4* fwts   = (float4*)alloc((size_t)EF * 16);
  uchar4* bcells = (uchar4*)alloc((size_t)EB * 4);
  float4* bwts   = (float4*)alloc((size_t)EB * 16);
  int* fhist = (int*)alloc((size_t)FBLK * 64 * 4);
  int* fbase = (int*)alloc((size_t)FBLK * 64 * 4);
  int* bhist = (int*)alloc((size_t)BBLK * 64 * 4);
  int* bbase = (int*)alloc((size_t)BBLK * 64 * 4);
  int* fcs = (int*)alloc(65 * 4);
  int* bcs = (int*)alloc(65 * 4);
  int* finstpos = (int*)alloc((size_t)TOTF * 4);
  int* fsrc     = (int*)alloc((size_t)TOTF * 4);
  float* fw     = (float*)alloc((size_t)TOTF * 4);
  int* binstpos = (int*)alloc((size_t)TOTB * 4);
  int* bsrc     = (int*)alloc((size_t)TOTB * 4);
  float* bw     = (float*)alloc((size_t)TOTB * 4);
  int* fthist  = (int*)alloc((size_t)NF * 4);
  int* ftstart = (int*)alloc((size_t)(NF + 1) * 4);
  int* ftcur   = (int*)alloc((size_t)NF * 4);
  int* ftedges = (int*)alloc((size_t)EF * 4);
  int* bthist  = (int*)alloc((size_t)NF * 4);
  int* btstart = (int*)alloc((size_t)(NF + 1) * 4);
  int* btcur   = (int*)alloc((size_t)NF * 4);
  int* btedges = (int*)alloc((size_t)EB * 4);
  float* msgB  = (float*)alloc((size_t)TOTB * 32 * 4);  // bdy stage-1 msgs, resident
  // fluid message buffer: everything that remains
  float* msgF = (float*)(w + off);
  size_t M = (ws_size > off) ? (ws_size - off) : 0;
  // chunking: 64-wide messages need 256 B/position
  long long Hcap = (long long)(M / 256) & ~511LL;
  int H = (Hcap < 512) ? 512 : (Hcap > TOTF ? TOTF : (int)Hcap);
  int S = (TOTF + H - 1) / H;

  hipMemsetAsync(fthist, 0, (size_t)NF * 4, stream);
  hipMemsetAsync(bthist, 0, (size_t)NF * 4, stream);

  // cell sort (fluid + boundary)
  basis_hist_kernel<<<FBLK, 256, 0, stream>>>(fp, fp, fi, fj, sup, -1.f, fcells, fwts, fhist);
  basis_hist_kernel<<<BBLK, 256, 0, stream>>>(fp, bp, bfi, bb, sup, 1.f, bcells, bwts, bhist);
  scan_kernel<<<1, 64, 0, stream>>>(fhist, FBLK, fbase, fcs);
  scan_kernel<<<1, 64, 0, stream>>>(bhist, BBLK, bbase, bcs);
  scatter_kernel<<<FBLK, 256, 0, stream>>>(fcells, fwts, fj, fbase, finstpos, fw, fsrc);
  scatter_kernel<<<BBLK, 256, 0, stream>>>(bcells, bwts, bb, bbase, binstpos, bw, bsrc);

  // target CSR (fluid edges by fi, boundary edges by bf)
  tgt_hist<<<FBLK, 256, 0, stream>>>(fi, EF, fthist);
  tgt_hist<<<BBLK, 256, 0, stream>>>(bfi, EB, bthist);
  csr_scan<<<1, 1024, 0, stream>>>(fthist, ftstart, ftcur);
  csr_scan<<<1, 1024, 0, stream>>>(bthist, btstart, btcur);
  tgt_scatter<<<FBLK, 256, 0, stream>>>(fi, EF, ftcur, ftedges);
  tgt_scatter<<<BBLK, 256, 0, stream>>>(bfi, EB, btcur, btedges);

  // Stage 1: boundary msgs resident, fluid msgs chunked
  msg_conv32<<<512, 256, 0, stream>>>(bsrc, bw, bcs, bfe, W1, msgB, 0, TOTB);
  for (int c = 0; c < S; c++) {
    int q0 = c * H, q1 = min(TOTF, (c + 1) * H);
    msg_conv32<<<2048, 256, 0, stream>>>(fsrc, fw, fcs, ff, W0, msgF, q0, q1);
    b1_stage1<<<NF / 4, 256, 0, stream>>>(ff, fc0, ftstart, ftedges, finstpos, msgF,
                                          btstart, btedges, binstpos, msgB, ans0,
                                          q0, q1, c == 0, c == S - 1);
  }
  // Stage 2: ans1 = relu(conv(ans0,W2) + ans0@fc1)
  for (int c = 0; c < S; c++) {
    int q0 = c * H, q1 = min(TOTF, (c + 1) * H);
    msg_conv64<96><<<2048, 256, 0, stream>>>(fsrc, fw, fcs, ans0, W2, msgF, q0, q1);
    b23<96, 0><<<NF / 4, 256, 0, stream>>>(ans0, fc1, ftstart, ftedges, finstpos, msgF,
                                           nullptr, ans1, q0, q1, c == 0, c == S - 1);
  }
  // Stage 3: ans2 = relu(conv(ans1,W3) + ans1@fc2 + ans1)
  for (int c = 0; c < S; c++) {
    int q0 = c * H, q1 = min(TOTF, (c + 1) * H);
    msg_conv64<64><<<2048, 256, 0, stream>>>(fsrc, fw, fcs, ans1, W3, msgF, q0, q1);
    b23<64, 1><<<NF / 4, 256, 0, stream>>>(ans1, fc2, ftstart, ftedges, finstpos, msgF,
                                           ans1, ans2, q0, q1, c == 0, c == S - 1);
  }
  // Stage 4: out = conv(ans2,W4) + ans2@fc3
  for (int c = 0; c < S; c++) {
    int q0 = c * H, q1 = min(TOTF, (c + 1) * H);
    msg_conv2<<<2048, 256, 0, stream>>>(fsrc, fw, fcs, ans2, W4, (float2*)msgF, q0, q1);
    b4_stage4<<<NF / 4, 256, 0, stream>>>(ans2, fc3, ftstart, ftedges, finstpos,
                                          (const float2*)msgF, outpre, out,
                                          q0, q1, c == 0, c == S - 1);
  }
}